// Round 5
// baseline (290.722 us; speedup 1.0000x reference)
//
#include <hip/hip_runtime.h>
#include <cstdint>
#include <cstddef>

#define N_NODES 50000
#define N_EDGES 1600000
#define TOT_E   (N_EDGES + N_NODES)
#define IN_DIM  256
#define HC      128
#define NHEAD   4
#define OUT_DIM 64

// bucket-radix CSR build
#define SHIFT   7
#define BSZ     128
#define NBUK    ((N_NODES + BSZ - 1) / BSZ)
#define CHUNK   8192
#define EPT     32
#define NCHUNK  ((TOT_E + CHUNK - 1) / CHUNK)
#define CAP     5120

// k1 MFMA tiling
#define XPAD 264   // bf16 elems per LDS row (256 + 8)
#define HPAD 132   // fp32 elems per LDS row in epilogue (128 + 4)

typedef __attribute__((ext_vector_type(8))) short bf16x8;
typedef __attribute__((ext_vector_type(4))) float f32x4;

static __device__ __forceinline__ uint16_t f2bf(float f) {
    uint32_t u = __float_as_uint(f);
    uint32_t r = (u + 0x7fffu + ((u >> 16) & 1u)) >> 16;   // RNE
    return (uint16_t)r;
}
static __device__ __forceinline__ float bf_lo(uint32_t u) {
    return __uint_as_float(u << 16);
}
static __device__ __forceinline__ float bf_hi(uint32_t u) {
    return __uint_as_float(u & 0xffff0000u);
}

// ---------------------------------------------------------------------------
// W prep: W fp32 [256][128] -> W^T bf16 [128][256]
// ---------------------------------------------------------------------------
__global__ __launch_bounds__(256) void w2bf(const float* __restrict__ W,
                                            uint16_t* __restrict__ wt) {
    int idx = blockIdx.x * 256 + threadIdx.x;   // n*256 + k
    int n = idx >> 8, k = idx & 255;
    wt[idx] = f2bf(W[(size_t)k * HC + n]);
}

// ---------------------------------------------------------------------------
// K1 (MFMA): h = x @ W, bf16 in, fp32 accum; fused a_src/a_dst epilogue.
// ---------------------------------------------------------------------------
__global__ __launch_bounds__(256) void k1_mfma(const float* __restrict__ x,
                                               const uint16_t* __restrict__ wt,
                                               const float* __restrict__ att_src,
                                               const float* __restrict__ att_dst,
                                               uint16_t* __restrict__ hb,
                                               float* __restrict__ a_src,
                                               float* __restrict__ a_dst) {
    __shared__ char smem[64 * 528];   // xs(bf16 64x264) == hs(f32 64x132)
    __shared__ float att_s[HC], att_d[HC];
    uint16_t* xs = (uint16_t*)smem;
    float*    hs = (float*)smem;

    const int tid  = threadIdx.x;
    const int wave = tid >> 6;
    const int lane = tid & 63;
    const int m    = lane & 15;
    const int q    = lane >> 4;
    const int row0 = blockIdx.x * 64;

    if (tid < HC) { att_s[tid] = att_src[tid]; att_d[tid] = att_dst[tid]; }

    for (int i = tid * 4; i < 64 * IN_DIM; i += 1024) {
        int r = i >> 8, c = i & 255;
        int gr = row0 + r;
        float4 v = make_float4(0.f, 0.f, 0.f, 0.f);
        if (gr < N_NODES) v = *(const float4*)(x + (size_t)gr * IN_DIM + c);
        uint32_t lo = (uint32_t)f2bf(v.x) | ((uint32_t)f2bf(v.y) << 16);
        uint32_t hi = (uint32_t)f2bf(v.z) | ((uint32_t)f2bf(v.w) << 16);
        *(uint2*)(xs + r * XPAD + c) = make_uint2(lo, hi);
    }
    __syncthreads();

    f32x4 acc[8];
    #pragma unroll
    for (int t = 0; t < 8; ++t) acc[t] = (f32x4){0.f, 0.f, 0.f, 0.f};

    const int arow = wave * 16 + m;
    #pragma unroll
    for (int ks = 0; ks < IN_DIM; ks += 32) {
        bf16x8 a = *(const bf16x8*)(xs + arow * XPAD + ks + q * 8);
        #pragma unroll
        for (int t = 0; t < 8; ++t) {
            bf16x8 b = *(const bf16x8*)(wt + (size_t)(t * 16 + m) * IN_DIM + ks + q * 8);
            acc[t] = __builtin_amdgcn_mfma_f32_16x16x32_bf16(a, b, acc[t], 0, 0, 0);
        }
    }
    __syncthreads();

    // C/D: col = lane&15, row = (lane>>4)*4 + reg
    #pragma unroll
    for (int t = 0; t < 8; ++t)
        #pragma unroll
        for (int r = 0; r < 4; ++r)
            hs[(wave * 16 + q * 4 + r) * HPAD + t * 16 + m] = acc[t][r];
    __syncthreads();

    for (int i = tid * 4; i < 64 * HC; i += 1024) {
        int r = i >> 7, c = i & 127;
        if (row0 + r < N_NODES) {
            float4 v = *(const float4*)(hs + r * HPAD + c);
            uint32_t lo = (uint32_t)f2bf(v.x) | ((uint32_t)f2bf(v.y) << 16);
            uint32_t hi = (uint32_t)f2bf(v.z) | ((uint32_t)f2bf(v.w) << 16);
            *(uint2*)(hb + (size_t)(row0 + r) * HC + c) = make_uint2(lo, hi);
        }
    }
    {
        int r = tid >> 2, hd = tid & 3;
        if (row0 + r < N_NODES) {
            float s = 0.f, d = 0.f;
            #pragma unroll
            for (int j = 0; j < 32; ++j) {
                float v = hs[r * HPAD + hd * 32 + j];
                s = fmaf(v, att_s[hd * 32 + j], s);
                d = fmaf(v, att_d[hd * 32 + j], d);
            }
            a_src[(row0 + r) * NHEAD + hd] = s;
            a_dst[(row0 + r) * NHEAD + hd] = d;
        }
    }
}

// ---------------------------------------------------------------------------
// P1: bucket histogram
// ---------------------------------------------------------------------------
__global__ __launch_bounds__(256) void p1_hist(const int* __restrict__ ei,
                                               int* __restrict__ gcount) {
    __shared__ int hist[NBUK];
    const int tid = threadIdx.x;
    for (int i = tid; i < NBUK; i += 256) hist[i] = 0;
    __syncthreads();
    const int base = blockIdx.x * CHUNK;
    #pragma unroll 4
    for (int k = 0; k < EPT; ++k) {
        int e = base + k * 256 + tid;
        if (e < TOT_E) {
            int dst = (e < N_EDGES) ? ei[N_EDGES + e] : (e - N_EDGES);
            atomicAdd(&hist[dst >> SHIFT], 1);
        }
    }
    __syncthreads();
    for (int i = tid; i < NBUK; i += 256)
        if (hist[i]) atomicAdd(&gcount[i], hist[i]);
}

// ---------------------------------------------------------------------------
// P2: 1-block scan of bucket counts
// ---------------------------------------------------------------------------
__global__ __launch_bounds__(512) void p2_scan(const int* __restrict__ gcount,
                                               int* __restrict__ gcur,
                                               int* __restrict__ bbase,
                                               int* __restrict__ rowptr) {
    __shared__ int ws[8];
    const int tid  = threadIdx.x;
    const int lane = tid & 63;
    const int wid  = tid >> 6;
    int v = (tid < NBUK) ? gcount[tid] : 0;
    int inc = v;
    #pragma unroll
    for (int d = 1; d < 64; d <<= 1) {
        int t = __shfl_up(inc, d, 64);
        if (lane >= d) inc += t;
    }
    if (lane == 63) ws[wid] = inc;
    __syncthreads();
    int wo = 0;
    for (int w = 0; w < wid; ++w) wo += ws[w];
    if (tid < NBUK) {
        int ex = wo + inc - v;
        gcur[tid]  = ex;
        bbase[tid] = ex;
    }
    if (tid == 0) { bbase[NBUK] = TOT_E; rowptr[N_NODES] = TOT_E; }
}

// ---------------------------------------------------------------------------
// P3: bin edges as packed words: src(16) | dstlocal(7)<<16 | bucket(9)<<23
// ---------------------------------------------------------------------------
__global__ __launch_bounds__(256) void p3_bin(const int* __restrict__ ei,
                                              int* __restrict__ gcur,
                                              uint32_t* __restrict__ binned) {
    __shared__ int hist[NBUK];
    __shared__ int lcur[NBUK];
    const int tid = threadIdx.x;
    for (int i = tid; i < NBUK; i += 256) hist[i] = 0;
    __syncthreads();

    uint32_t wreg[EPT];
    const int base = blockIdx.x * CHUNK;
    #pragma unroll
    for (int k = 0; k < EPT; ++k) {
        int e = base + k * 256 + tid;
        uint32_t word = 0xFFFFFFFFu;
        if (e < TOT_E) {
            int src, dst;
            if (e < N_EDGES) { src = ei[e]; dst = ei[N_EDGES + e]; }
            else             { src = e - N_EDGES; dst = src; }
            int b = dst >> SHIFT;
            word = (uint32_t)src | ((uint32_t)(dst & (BSZ - 1)) << 16)
                 | ((uint32_t)b << 23);
            atomicAdd(&hist[b], 1);
        }
        wreg[k] = word;
    }
    __syncthreads();
    for (int i = tid; i < NBUK; i += 256) {
        int c = hist[i];
        lcur[i] = c ? atomicAdd(&gcur[i], c) : 0;
    }
    __syncthreads();
    #pragma unroll
    for (int k = 0; k < EPT; ++k) {
        uint32_t word = wreg[k];
        if (word != 0xFFFFFFFFu) {
            int b = (int)(word >> 23);
            int pos = atomicAdd(&lcur[b], 1);
            binned[pos] = word;
        }
    }
}

// ---------------------------------------------------------------------------
// P4: per-bucket: LDS stage + 128-node count/scan -> rowptr + csr
// ---------------------------------------------------------------------------
__global__ __launch_bounds__(256) void p4_csr(const uint32_t* __restrict__ binned,
                                              const int* __restrict__ bbase,
                                              int* __restrict__ rowptr,
                                              int* __restrict__ csr_src) {
    __shared__ uint32_t ew[CAP];
    __shared__ int ncnt[BSZ];
    __shared__ int ncur[BSZ];
    __shared__ int wtot;
    const int b    = blockIdx.x;
    const int base = bbase[b];
    const int cnt  = bbase[b + 1] - base;
    const int tid  = threadIdx.x;

    for (int i = tid; i < BSZ; i += 256) ncnt[i] = 0;
    __syncthreads();

    const bool fit = (cnt <= CAP);
    for (int i = tid; i < cnt; i += 256) {
        uint32_t word = binned[base + i];
        if (fit) ew[i] = word;
        atomicAdd(&ncnt[(word >> 16) & (BSZ - 1)], 1);
    }
    __syncthreads();

    int v = 0, inc = 0;
    if (tid < BSZ) {
        v = ncnt[tid];
        inc = v;
        int lane = tid & 63;
        #pragma unroll
        for (int d = 1; d < 64; d <<= 1) {
            int t = __shfl_up(inc, d, 64);
            if (lane >= d) inc += t;
        }
        if (tid == 63) wtot = inc;
    }
    __syncthreads();
    if (tid < BSZ) {
        int ex = inc - v + ((tid >= 64) ? wtot : 0);
        int node = b * BSZ + tid;
        if (node < N_NODES) rowptr[node] = base + ex;
        ncur[tid] = ex;
    }
    __syncthreads();

    for (int i = tid; i < cnt; i += 256) {
        uint32_t word = fit ? ew[i] : binned[base + i];
        int local = (word >> 16) & (BSZ - 1);
        int r = atomicAdd(&ncur[local], 1);
        csr_src[base + r] = (int)(word & 0xFFFFu);
    }
}

// ---------------------------------------------------------------------------
// K6: wave-cooperative softmax aggregation. 4 waves/block, 1 node/wave.
// Phase 1 (per 16 edges): lane (j=lane&15, h=lane>>4) computes w once;
// per-head l accumulated on those lanes (xor-reduced at the end).
// Phase 2: w via ds_bpermute (DS pipe), src via v_readlane -> SGPR base so
// the hb gather is global_load_dword v, laneoff, s[base] (no VALU addr math).
// Output act packed bf16.
// ---------------------------------------------------------------------------
__global__ __launch_bounds__(256) void k6_agg(const uint32_t* __restrict__ hb32,
                                              const float* __restrict__ a_src,
                                              const float* __restrict__ a_dst,
                                              const int* __restrict__ rowptr,
                                              const int* __restrict__ csr_src,
                                              const float* __restrict__ bias,
                                              uint32_t* __restrict__ actb) {
    const int node = blockIdx.x * 4 + (threadIdx.x >> 6);   // 50000 % 4 == 0
    const int lane = threadIdx.x & 63;
    const int head = lane >> 4;
    const int j    = lane & 15;
    const int wb4  = (lane & 48) << 2;      // bpermute byte base

    const float ad  = a_dst[node * NHEAD + head];
    const int   beg = rowptr[node];
    const int   end = rowptr[node + 1];

    float l_part = 0.f, acc0 = 0.f, acc1 = 0.f;

    int p = beg;
    for (; p + 16 <= end; p += 16) {
        int sv = csr_src[p + j];            // 16 srcs, replicated over 4 head groups
        float e = a_src[sv * NHEAD + head] + ad;
        e = fmaxf(e, 0.2f * e);             // LeakyReLU(0.2)
        float w = __expf(e);
        l_part += w;
        uint32_t wbits = __float_as_uint(w);
        #pragma unroll
        for (int t = 0; t < 16; ++t) {
            float wv = __uint_as_float(__builtin_amdgcn_ds_bpermute(wb4 + 4 * t, (int)wbits));
            int s = __builtin_amdgcn_readlane(sv, t);       // SGPR broadcast
            uint32_t u = hb32[(size_t)s * 64 + lane];       // saddr + lane*4
            acc0 = fmaf(wv, bf_lo(u), acc0);
            acc1 = fmaf(wv, bf_hi(u), acc1);
        }
    }
    int rem = end - p;                      // 0..15, uniform across the wave
    if (rem > 0) {
        int idx = p + (j < rem ? j : 0);
        int sv = csr_src[idx];
        float e = a_src[sv * NHEAD + head] + ad;
        e = fmaxf(e, 0.2f * e);
        float w = (j < rem) ? __expf(e) : 0.f;
        l_part += w;
        uint32_t wbits = __float_as_uint(w);
        for (int t = 0; t < rem; ++t) {     // t uniform
            float wv = __uint_as_float(__builtin_amdgcn_ds_bpermute(wb4 + 4 * t, (int)wbits));
            int s = __builtin_amdgcn_readlane(sv, t);
            uint32_t u = hb32[(size_t)s * 64 + lane];
            acc0 = fmaf(wv, bf_lo(u), acc0);
            acc1 = fmaf(wv, bf_hi(u), acc1);
        }
    }

    // reduce l over the 16 lanes of this head group
    #pragma unroll
    for (int o = 1; o < 16; o <<= 1) l_part += __shfl_xor(l_part, o, 64);

    const int c0 = lane << 1;
    float inv = 1.f / l_part;               // self loop => l > 0
    float o0 = acc0 * inv + bias[c0];
    float o1 = acc1 * inv + bias[c0 + 1];
    o0 = (o0 > 0.f) ? o0 : (__expf(o0) - 1.f);
    o1 = (o1 > 0.f) ? o1 : (__expf(o1) - 1.f);
    actb[(size_t)node * 64 + lane] = (uint32_t)f2bf(o0) | ((uint32_t)f2bf(o1) << 16);
}

// ---------------------------------------------------------------------------
// K7: out = act @ lin_W + lin_b   [N,128] @ [128,64]; act read as bf16
// ---------------------------------------------------------------------------
__global__ __launch_bounds__(512) void k7_out(const uint32_t* __restrict__ actb,
                                              const float* __restrict__ linW,
                                              const float* __restrict__ linb,
                                              float* __restrict__ out) {
    __shared__ float sW[HC * OUT_DIM];   // 32 KB
    __shared__ float srow[32 * HC];      // 16 KB
    const int tid   = threadIdx.x;
    const int node0 = blockIdx.x * 32;

    for (int i = tid * 4; i < HC * OUT_DIM; i += 512 * 4)
        *(float4*)(sW + i) = *(const float4*)(linW + i);
    {
        int i = tid * 4;                 // word index: 32 rows x 64 words
        int r = i >> 6, cw = i & 63;
        int node = node0 + r;
        uint4 v = make_uint4(0, 0, 0, 0);
        if (node < N_NODES) v = *(const uint4*)(actb + (size_t)node * 64 + cw);
        float* d = srow + r * HC + cw * 2;
        d[0] = bf_lo(v.x); d[1] = bf_hi(v.x);
        d[2] = bf_lo(v.y); d[3] = bf_hi(v.y);
        d[4] = bf_lo(v.z); d[5] = bf_hi(v.z);
        d[6] = bf_lo(v.w); d[7] = bf_hi(v.w);
    }
    __syncthreads();

    const int r    = tid >> 4;
    const int colb = (tid & 15) << 2;
    float4 acc = *(const float4*)(linb + colb);
    const float* rp = srow + r * HC;

    #pragma unroll
    for (int k = 0; k < HC; k += 4) {
        float4 xv = *(const float4*)(rp + k);
        float4 w0 = *(const float4*)(sW + (k + 0) * OUT_DIM + colb);
        float4 w1 = *(const float4*)(sW + (k + 1) * OUT_DIM + colb);
        float4 w2 = *(const float4*)(sW + (k + 2) * OUT_DIM + colb);
        float4 w3 = *(const float4*)(sW + (k + 3) * OUT_DIM + colb);
        acc.x += xv.x * w0.x; acc.x += xv.y * w1.x; acc.x += xv.z * w2.x; acc.x += xv.w * w3.x;
        acc.y += xv.x * w0.y; acc.y += xv.y * w1.y; acc.y += xv.z * w2.y; acc.y += xv.w * w3.y;
        acc.z += xv.x * w0.z; acc.z += xv.y * w1.z; acc.z += xv.z * w2.z; acc.z += xv.w * w3.z;
        acc.w += xv.x * w0.w; acc.w += xv.y * w1.w; acc.w += xv.z * w2.w; acc.w += xv.w * w3.w;
    }

    int node = node0 + r;
    if (node < N_NODES)
        *(float4*)(out + (size_t)node * OUT_DIM + colb) = acc;
}

// ---------------------------------------------------------------------------
extern "C" void kernel_launch(void* const* d_in, const int* in_sizes, int n_in,
                              void* d_out, int out_size, void* d_ws, size_t ws_size,
                              hipStream_t stream) {
    (void)in_sizes; (void)n_in; (void)out_size; (void)ws_size;
    const float* x       = (const float*)d_in[0];
    const int*   ei      = (const int*)d_in[1];
    const float* W       = (const float*)d_in[2];
    const float* att_src = (const float*)d_in[3];
    const float* att_dst = (const float*)d_in[4];
    const float* bias    = (const float*)d_in[5];
    const float* linW    = (const float*)d_in[6];
    const float* linb    = (const float*)d_in[7];
    float*       out     = (float*)d_out;

    char*  ws  = (char*)d_ws;
    size_t off = 0;
    auto alloc = [&](size_t bytes) -> void* {
        void* p = ws + off;
        off += (bytes + 255) & ~(size_t)255;
        return p;
    };
    uint16_t* hb     = (uint16_t*)alloc((size_t)N_NODES * HC * 2);
    uint16_t* wt     = (uint16_t*)alloc((size_t)HC * IN_DIM * 2);
    uint32_t* actb   = (uint32_t*)alloc((size_t)N_NODES * 64 * 4);
    float*    a_src  = (float*)alloc((size_t)N_NODES * NHEAD * 4);
    float*    a_dst  = (float*)alloc((size_t)N_NODES * NHEAD * 4);
    int*      gcount = (int*)alloc((size_t)(NBUK + 1) * 4);
    int*      gcur   = (int*)alloc((size_t)(NBUK + 1) * 4);
    int*      bbase  = (int*)alloc((size_t)(NBUK + 1) * 4);
    int*      rowptr = (int*)alloc((size_t)(N_NODES + 1) * 4);
    uint32_t* binned = (uint32_t*)alloc((size_t)TOT_E * 4);
    int*      csr    = (int*)alloc((size_t)TOT_E * 4);

    hipMemsetAsync(gcount, 0, (size_t)(NBUK + 1) * 4, stream);

    w2bf<<<(HC * IN_DIM) / 256, 256, 0, stream>>>(W, wt);
    k1_mfma<<<(N_NODES + 63) / 64, 256, 0, stream>>>(x, wt, att_src, att_dst,
                                                     hb, a_src, a_dst);
    p1_hist<<<NCHUNK, 256, 0, stream>>>(ei, gcount);
    p2_scan<<<1, 512, 0, stream>>>(gcount, gcur, bbase, rowptr);
    p3_bin<<<NCHUNK, 256, 0, stream>>>(ei, gcur, binned);
    p4_csr<<<NBUK, 256, 0, stream>>>(binned, bbase, rowptr, csr);
    k6_agg<<<N_NODES / 4, 256, 0, stream>>>((const uint32_t*)hb, a_src, a_dst,
                                            rowptr, csr, bias, actb);
    k7_out<<<(N_NODES + 31) / 32, 512, 0, stream>>>(actb, linW, linb, out);
}

// Round 6
// 271.405 us; speedup vs baseline: 1.0712x; 1.0712x over previous
//
#include <hip/hip_runtime.h>
#include <cstdint>
#include <cstddef>

#define N_NODES 50000
#define N_EDGES 1600000
#define TOT_E   (N_EDGES + N_NODES)
#define IN_DIM  256
#define HC      128
#define NHEAD   4
#define OUT_DIM 64

// bucket-radix CSR build (fixed-stride buckets: no global scan)
#define SHIFT   7
#define BSZ     128
#define NBUK    ((N_NODES + BSZ - 1) / BSZ)      // 391
#define CHUNK   8192
#define EPT     32
#define NCHUNK  ((TOT_E + CHUNK - 1) / CHUNK)    // 202
#define CAP     6144                             // bucket capacity (mean 4220, +29 sd)

// k1 MFMA tiling
#define XPAD 264   // bf16 elems per LDS row (256 + 8)
#define HPAD 132   // fp32 elems per LDS row in epilogue (128 + 4)

typedef __attribute__((ext_vector_type(8))) short bf16x8;
typedef __attribute__((ext_vector_type(4))) float f32x4;

static __device__ __forceinline__ uint16_t f2bf(float f) {
    uint32_t u = __float_as_uint(f);
    uint32_t r = (u + 0x7fffu + ((u >> 16) & 1u)) >> 16;   // RNE
    return (uint16_t)r;
}
static __device__ __forceinline__ float bf_lo(uint32_t u) {
    return __uint_as_float(u << 16);
}
static __device__ __forceinline__ float bf_hi(uint32_t u) {
    return __uint_as_float(u & 0xffff0000u);
}

// ---------------------------------------------------------------------------
// W prep: W fp32 [256][128] -> W^T bf16 [128][256]
// ---------------------------------------------------------------------------
__global__ __launch_bounds__(256) void w2bf(const float* __restrict__ W,
                                            uint16_t* __restrict__ wt) {
    int idx = blockIdx.x * 256 + threadIdx.x;   // n*256 + k
    int n = idx >> 8, k = idx & 255;
    wt[idx] = f2bf(W[(size_t)k * HC + n]);
}

// ---------------------------------------------------------------------------
// K1 (MFMA): h = x @ W, bf16 in, fp32 accum; fused a_src/a_dst epilogue.
// ---------------------------------------------------------------------------
__global__ __launch_bounds__(256) void k1_mfma(const float* __restrict__ x,
                                               const uint16_t* __restrict__ wt,
                                               const float* __restrict__ att_src,
                                               const float* __restrict__ att_dst,
                                               uint16_t* __restrict__ hb,
                                               float* __restrict__ a_src,
                                               float* __restrict__ a_dst) {
    __shared__ char smem[64 * 528];   // xs(bf16 64x264) == hs(f32 64x132)
    __shared__ float att_s[HC], att_d[HC];
    uint16_t* xs = (uint16_t*)smem;
    float*    hs = (float*)smem;

    const int tid  = threadIdx.x;
    const int wave = tid >> 6;
    const int lane = tid & 63;
    const int m    = lane & 15;
    const int q    = lane >> 4;
    const int row0 = blockIdx.x * 64;

    if (tid < HC) { att_s[tid] = att_src[tid]; att_d[tid] = att_dst[tid]; }

    for (int i = tid * 4; i < 64 * IN_DIM; i += 1024) {
        int r = i >> 8, c = i & 255;
        int gr = row0 + r;
        float4 v = make_float4(0.f, 0.f, 0.f, 0.f);
        if (gr < N_NODES) v = *(const float4*)(x + (size_t)gr * IN_DIM + c);
        uint32_t lo = (uint32_t)f2bf(v.x) | ((uint32_t)f2bf(v.y) << 16);
        uint32_t hi = (uint32_t)f2bf(v.z) | ((uint32_t)f2bf(v.w) << 16);
        *(uint2*)(xs + r * XPAD + c) = make_uint2(lo, hi);
    }
    __syncthreads();

    f32x4 acc[8];
    #pragma unroll
    for (int t = 0; t < 8; ++t) acc[t] = (f32x4){0.f, 0.f, 0.f, 0.f};

    const int arow = wave * 16 + m;
    #pragma unroll
    for (int ks = 0; ks < IN_DIM; ks += 32) {
        bf16x8 a = *(const bf16x8*)(xs + arow * XPAD + ks + q * 8);
        #pragma unroll
        for (int t = 0; t < 8; ++t) {
            bf16x8 b = *(const bf16x8*)(wt + (size_t)(t * 16 + m) * IN_DIM + ks + q * 8);
            acc[t] = __builtin_amdgcn_mfma_f32_16x16x32_bf16(a, b, acc[t], 0, 0, 0);
        }
    }
    __syncthreads();

    // C/D: col = lane&15, row = (lane>>4)*4 + reg
    #pragma unroll
    for (int t = 0; t < 8; ++t)
        #pragma unroll
        for (int r = 0; r < 4; ++r)
            hs[(wave * 16 + q * 4 + r) * HPAD + t * 16 + m] = acc[t][r];
    __syncthreads();

    for (int i = tid * 4; i < 64 * HC; i += 1024) {
        int r = i >> 7, c = i & 127;
        if (row0 + r < N_NODES) {
            float4 v = *(const float4*)(hs + r * HPAD + c);
            uint32_t lo = (uint32_t)f2bf(v.x) | ((uint32_t)f2bf(v.y) << 16);
            uint32_t hi = (uint32_t)f2bf(v.z) | ((uint32_t)f2bf(v.w) << 16);
            *(uint2*)(hb + (size_t)(row0 + r) * HC + c) = make_uint2(lo, hi);
        }
    }
    {
        int r = tid >> 2, hd = tid & 3;
        if (row0 + r < N_NODES) {
            float s = 0.f, d = 0.f;
            #pragma unroll
            for (int j = 0; j < 32; ++j) {
                float v = hs[r * HPAD + hd * 32 + j];
                s = fmaf(v, att_s[hd * 32 + j], s);
                d = fmaf(v, att_d[hd * 32 + j], d);
            }
            a_src[(row0 + r) * NHEAD + hd] = s;
            a_dst[(row0 + r) * NHEAD + hd] = d;
        }
    }
}

// ---------------------------------------------------------------------------
// P3: bin edges into FIXED-STRIDE bucket regions (binned[b*CAP + pos]).
// word = src(16) | dstlocal(7)<<16 | bucket(9)<<23. One global atomic per
// (block,bucket); per-edge work is LDS atomics only. No pre-count, no scan.
// ---------------------------------------------------------------------------
__global__ __launch_bounds__(256) void p3_bin(const int* __restrict__ ei,
                                              int* __restrict__ gcur,
                                              uint32_t* __restrict__ binned) {
    __shared__ int hist[NBUK];
    __shared__ int lcur[NBUK];
    const int tid = threadIdx.x;
    for (int i = tid; i < NBUK; i += 256) hist[i] = 0;
    __syncthreads();

    uint32_t wreg[EPT];
    const int base = blockIdx.x * CHUNK;
    #pragma unroll
    for (int k = 0; k < EPT; ++k) {
        int e = base + k * 256 + tid;
        uint32_t word = 0xFFFFFFFFu;
        if (e < TOT_E) {
            int src, dst;
            if (e < N_EDGES) { src = ei[e]; dst = ei[N_EDGES + e]; }
            else             { src = e - N_EDGES; dst = src; }
            int b = dst >> SHIFT;
            word = (uint32_t)src | ((uint32_t)(dst & (BSZ - 1)) << 16)
                 | ((uint32_t)b << 23);
            atomicAdd(&hist[b], 1);
        }
        wreg[k] = word;
    }
    __syncthreads();
    for (int i = tid; i < NBUK; i += 256) {
        int c = hist[i];
        lcur[i] = c ? atomicAdd(&gcur[i], c) : 0;   // within-bucket base
    }
    __syncthreads();
    #pragma unroll
    for (int k = 0; k < EPT; ++k) {
        uint32_t word = wreg[k];
        if (word != 0xFFFFFFFFu) {
            int b = (int)(word >> 23);
            int pos = atomicAdd(&lcur[b], 1);
            if (pos < CAP) binned[(size_t)b * CAP + pos] = word;
        }
    }
}

// ---------------------------------------------------------------------------
// P4: per-bucket: LDS stage + 128-node count/scan -> rbeg/rend + grouped csr
// (strided layout: all indices relative to b*CAP; no global contiguity).
// ---------------------------------------------------------------------------
__global__ __launch_bounds__(256) void p4_csr(const uint32_t* __restrict__ binned,
                                              const int* __restrict__ gcur,
                                              int* __restrict__ rbeg,
                                              int* __restrict__ rend,
                                              int* __restrict__ csr_src) {
    __shared__ uint32_t ew[CAP];   // 24 KB
    __shared__ int ncnt[BSZ];
    __shared__ int ncur[BSZ];
    __shared__ int wtot;
    const int b    = blockIdx.x;
    const int base = b * CAP;
    int cnt = gcur[b];
    if (cnt > CAP) cnt = CAP;
    const int tid  = threadIdx.x;

    for (int i = tid; i < BSZ; i += 256) ncnt[i] = 0;
    __syncthreads();

    for (int i = tid; i < cnt; i += 256) {
        uint32_t word = binned[base + i];
        ew[i] = word;
        atomicAdd(&ncnt[(word >> 16) & (BSZ - 1)], 1);
    }
    __syncthreads();

    int v = 0, inc = 0;
    if (tid < BSZ) {
        v = ncnt[tid];
        inc = v;
        int lane = tid & 63;
        #pragma unroll
        for (int d = 1; d < 64; d <<= 1) {
            int t = __shfl_up(inc, d, 64);
            if (lane >= d) inc += t;
        }
        if (tid == 63) wtot = inc;
    }
    __syncthreads();
    if (tid < BSZ) {
        int ex = inc - v + ((tid >= 64) ? wtot : 0);
        int node = b * BSZ + tid;
        if (node < N_NODES) {
            rbeg[node] = base + ex;
            rend[node] = base + ex + v;
        }
        ncur[tid] = ex;
    }
    __syncthreads();

    for (int i = tid; i < cnt; i += 256) {
        uint32_t word = ew[i];
        int local = (word >> 16) & (BSZ - 1);
        int r = atomicAdd(&ncur[local], 1);
        csr_src[base + r] = (int)(word & 0xFFFFu);
    }
}

// ---------------------------------------------------------------------------
// K6: per-node softmax aggregation + bias + ELU. R4 structure (per-lane,
// redundant exp buys memory-level parallelism), unroll 8, 2 nodes/block
// (128 thr) for occupancy, bf16 act output.
// ---------------------------------------------------------------------------
__global__ __launch_bounds__(128) void k6_agg(const uint32_t* __restrict__ hb32,
                                              const float* __restrict__ a_src,
                                              const float* __restrict__ a_dst,
                                              const int* __restrict__ rbeg,
                                              const int* __restrict__ rend,
                                              const int* __restrict__ csr_src,
                                              const float* __restrict__ bias,
                                              uint32_t* __restrict__ actb) {
    const int node = blockIdx.x * 2 + (threadIdx.x >> 6);   // 50000 % 2 == 0
    const int lane = threadIdx.x & 63;
    const int head = lane >> 4;

    const float ad  = a_dst[node * NHEAD + head];
    const uint32_t* hbl = hb32 + lane;      // hoisted lane offset
    const float*    ash = a_src + head;

    int p   = rbeg[node];
    const int end = rend[node];

    float l = 0.f, acc0 = 0.f, acc1 = 0.f;

    for (; p + 8 <= end; p += 8) {
        int s0 = csr_src[p + 0];
        int s1 = csr_src[p + 1];
        int s2 = csr_src[p + 2];
        int s3 = csr_src[p + 3];
        int s4 = csr_src[p + 4];
        int s5 = csr_src[p + 5];
        int s6 = csr_src[p + 6];
        int s7 = csr_src[p + 7];
        float e0 = ash[s0 * NHEAD] + ad;
        float e1 = ash[s1 * NHEAD] + ad;
        float e2 = ash[s2 * NHEAD] + ad;
        float e3 = ash[s3 * NHEAD] + ad;
        float e4 = ash[s4 * NHEAD] + ad;
        float e5 = ash[s5 * NHEAD] + ad;
        float e6 = ash[s6 * NHEAD] + ad;
        float e7 = ash[s7 * NHEAD] + ad;
        uint32_t u0 = hbl[(size_t)s0 * 64];
        uint32_t u1 = hbl[(size_t)s1 * 64];
        uint32_t u2 = hbl[(size_t)s2 * 64];
        uint32_t u3 = hbl[(size_t)s3 * 64];
        uint32_t u4 = hbl[(size_t)s4 * 64];
        uint32_t u5 = hbl[(size_t)s5 * 64];
        uint32_t u6 = hbl[(size_t)s6 * 64];
        uint32_t u7 = hbl[(size_t)s7 * 64];
        e0 = fmaxf(e0, 0.2f * e0);
        e1 = fmaxf(e1, 0.2f * e1);
        e2 = fmaxf(e2, 0.2f * e2);
        e3 = fmaxf(e3, 0.2f * e3);
        e4 = fmaxf(e4, 0.2f * e4);
        e5 = fmaxf(e5, 0.2f * e5);
        e6 = fmaxf(e6, 0.2f * e6);
        e7 = fmaxf(e7, 0.2f * e7);
        float w0 = __expf(e0), w1 = __expf(e1);
        float w2 = __expf(e2), w3 = __expf(e3);
        float w4 = __expf(e4), w5 = __expf(e5);
        float w6 = __expf(e6), w7 = __expf(e7);
        l += ((w0 + w1) + (w2 + w3)) + ((w4 + w5) + (w6 + w7));
        acc0 = fmaf(w0, bf_lo(u0), acc0);
        acc1 = fmaf(w0, bf_hi(u0), acc1);
        acc0 = fmaf(w1, bf_lo(u1), acc0);
        acc1 = fmaf(w1, bf_hi(u1), acc1);
        acc0 = fmaf(w2, bf_lo(u2), acc0);
        acc1 = fmaf(w2, bf_hi(u2), acc1);
        acc0 = fmaf(w3, bf_lo(u3), acc0);
        acc1 = fmaf(w3, bf_hi(u3), acc1);
        acc0 = fmaf(w4, bf_lo(u4), acc0);
        acc1 = fmaf(w4, bf_hi(u4), acc1);
        acc0 = fmaf(w5, bf_lo(u5), acc0);
        acc1 = fmaf(w5, bf_hi(u5), acc1);
        acc0 = fmaf(w6, bf_lo(u6), acc0);
        acc1 = fmaf(w6, bf_hi(u6), acc1);
        acc0 = fmaf(w7, bf_lo(u7), acc0);
        acc1 = fmaf(w7, bf_hi(u7), acc1);
    }
    for (; p < end; ++p) {
        int s = csr_src[p];
        float e = ash[s * NHEAD] + ad;
        e = fmaxf(e, 0.2f * e);
        float w = __expf(e);
        uint32_t u = hbl[(size_t)s * 64];
        l += w;
        acc0 = fmaf(w, bf_lo(u), acc0);
        acc1 = fmaf(w, bf_hi(u), acc1);
    }

    const int c0 = lane << 1;
    float inv = 1.f / l;                    // self loop => l > 0
    float o0 = acc0 * inv + bias[c0];
    float o1 = acc1 * inv + bias[c0 + 1];
    o0 = (o0 > 0.f) ? o0 : (__expf(o0) - 1.f);
    o1 = (o1 > 0.f) ? o1 : (__expf(o1) - 1.f);
    actb[(size_t)node * 64 + lane] = (uint32_t)f2bf(o0) | ((uint32_t)f2bf(o1) << 16);
}

// ---------------------------------------------------------------------------
// K7: out = act @ lin_W + lin_b   [N,128] @ [128,64]; act read as bf16
// ---------------------------------------------------------------------------
__global__ __launch_bounds__(512) void k7_out(const uint32_t* __restrict__ actb,
                                              const float* __restrict__ linW,
                                              const float* __restrict__ linb,
                                              float* __restrict__ out) {
    __shared__ float sW[HC * OUT_DIM];   // 32 KB
    __shared__ float srow[32 * HC];      // 16 KB
    const int tid   = threadIdx.x;
    const int node0 = blockIdx.x * 32;

    for (int i = tid * 4; i < HC * OUT_DIM; i += 512 * 4)
        *(float4*)(sW + i) = *(const float4*)(linW + i);
    {
        int i = tid * 4;                 // word index: 32 rows x 64 words
        int r = i >> 6, cw = i & 63;
        int node = node0 + r;
        uint4 v = make_uint4(0, 0, 0, 0);
        if (node < N_NODES) v = *(const uint4*)(actb + (size_t)node * 64 + cw);
        float* d = srow + r * HC + cw * 2;
        d[0] = bf_lo(v.x); d[1] = bf_hi(v.x);
        d[2] = bf_lo(v.y); d[3] = bf_hi(v.y);
        d[4] = bf_lo(v.z); d[5] = bf_hi(v.z);
        d[6] = bf_lo(v.w); d[7] = bf_hi(v.w);
    }
    __syncthreads();

    const int r    = tid >> 4;
    const int colb = (tid & 15) << 2;
    float4 acc = *(const float4*)(linb + colb);
    const float* rp = srow + r * HC;

    #pragma unroll
    for (int k = 0; k < HC; k += 4) {
        float4 xv = *(const float4*)(rp + k);
        float4 w0 = *(const float4*)(sW + (k + 0) * OUT_DIM + colb);
        float4 w1 = *(const float4*)(sW + (k + 1) * OUT_DIM + colb);
        float4 w2 = *(const float4*)(sW + (k + 2) * OUT_DIM + colb);
        float4 w3 = *(const float4*)(sW + (k + 3) * OUT_DIM + colb);
        acc.x += xv.x * w0.x; acc.x += xv.y * w1.x; acc.x += xv.z * w2.x; acc.x += xv.w * w3.x;
        acc.y += xv.x * w0.y; acc.y += xv.y * w1.y; acc.y += xv.z * w2.y; acc.y += xv.w * w3.y;
        acc.z += xv.x * w0.z; acc.z += xv.y * w1.z; acc.z += xv.z * w2.z; acc.z += xv.w * w3.z;
        acc.w += xv.x * w0.w; acc.w += xv.y * w1.w; acc.w += xv.z * w2.w; acc.w += xv.w * w3.w;
    }

    int node = node0 + r;
    if (node < N_NODES)
        *(float4*)(out + (size_t)node * OUT_DIM + colb) = acc;
}

// ---------------------------------------------------------------------------
extern "C" void kernel_launch(void* const* d_in, const int* in_sizes, int n_in,
                              void* d_out, int out_size, void* d_ws, size_t ws_size,
                              hipStream_t stream) {
    (void)in_sizes; (void)n_in; (void)out_size; (void)ws_size;
    const float* x       = (const float*)d_in[0];
    const int*   ei      = (const int*)d_in[1];
    const float* W       = (const float*)d_in[2];
    const float* att_src = (const float*)d_in[3];
    const float* att_dst = (const float*)d_in[4];
    const float* bias    = (const float*)d_in[5];
    const float* linW    = (const float*)d_in[6];
    const float* linb    = (const float*)d_in[7];
    float*       out     = (float*)d_out;

    char*  ws  = (char*)d_ws;
    size_t off = 0;
    auto alloc = [&](size_t bytes) -> void* {
        void* p = ws + off;
        off += (bytes + 255) & ~(size_t)255;
        return p;
    };
    uint16_t* hb     = (uint16_t*)alloc((size_t)N_NODES * HC * 2);
    uint16_t* wt     = (uint16_t*)alloc((size_t)HC * IN_DIM * 2);
    uint32_t* actb   = (uint32_t*)alloc((size_t)N_NODES * 64 * 4);
    float*    a_src  = (float*)alloc((size_t)N_NODES * NHEAD * 4);
    float*    a_dst  = (float*)alloc((size_t)N_NODES * NHEAD * 4);
    int*      gcur   = (int*)alloc((size_t)NBUK * 4);
    int*      rbeg   = (int*)alloc((size_t)N_NODES * 4);
    int*      rend   = (int*)alloc((size_t)N_NODES * 4);
    uint32_t* binned = (uint32_t*)alloc((size_t)NBUK * CAP * 4);
    int*      csr    = (int*)alloc((size_t)NBUK * CAP * 4);

    hipMemsetAsync(gcur, 0, (size_t)NBUK * 4, stream);

    w2bf<<<(HC * IN_DIM) / 256, 256, 0, stream>>>(W, wt);
    k1_mfma<<<(N_NODES + 63) / 64, 256, 0, stream>>>(x, wt, att_src, att_dst,
                                                     hb, a_src, a_dst);
    p3_bin<<<NCHUNK, 256, 0, stream>>>(ei, gcur, binned);
    p4_csr<<<NBUK, 256, 0, stream>>>(binned, gcur, rbeg, rend, csr);
    k6_agg<<<N_NODES / 2, 128, 0, stream>>>((const uint32_t*)hb, a_src, a_dst,
                                            rbeg, rend, csr, bias, actb);
    k7_out<<<(N_NODES + 31) / 32, 512, 0, stream>>>(actb, linW, linb, out);
}

// Round 7
// 265.114 us; speedup vs baseline: 1.0966x; 1.0237x over previous
//
#include <hip/hip_runtime.h>
#include <cstdint>
#include <cstddef>

#define N_NODES 50000
#define N_EDGES 1600000
#define TOT_E   (N_EDGES + N_NODES)
#define IN_DIM  256
#define HC      128
#define NHEAD   4
#define OUT_DIM 64

// bucket-radix CSR build (fixed-stride buckets: no global scan)
#define SHIFT   7
#define BSZ     128
#define NBUK    ((N_NODES + BSZ - 1) / BSZ)      // 391
#define CHUNK   2048
#define EPT     8                                // CHUNK / 256
#define NCHUNK  ((TOT_E + CHUNK - 1) / CHUNK)    // 806
#define CAP     6144                             // bucket capacity (mean 4220, +29 sd)

// k1 MFMA tiling
#define XPAD 264   // bf16 elems per LDS row (256 + 8)
#define HPAD 132   // fp32 elems per LDS row in epilogue (128 + 4)

typedef __attribute__((ext_vector_type(8))) short bf16x8;
typedef __attribute__((ext_vector_type(4))) float f32x4;

static __device__ __forceinline__ uint16_t f2bf(float f) {
    uint32_t u = __float_as_uint(f);
    uint32_t r = (u + 0x7fffu + ((u >> 16) & 1u)) >> 16;   // RNE
    return (uint16_t)r;
}
static __device__ __forceinline__ float bf_lo(uint32_t u) {
    return __uint_as_float(u << 16);
}
static __device__ __forceinline__ float bf_hi(uint32_t u) {
    return __uint_as_float(u & 0xffff0000u);
}

// ---------------------------------------------------------------------------
// W prep: W fp32 [256][128] -> W^T bf16 [128][256]
// ---------------------------------------------------------------------------
__global__ __launch_bounds__(256) void w2bf(const float* __restrict__ W,
                                            uint16_t* __restrict__ wt) {
    int idx = blockIdx.x * 256 + threadIdx.x;   // n*256 + k
    int n = idx >> 8, k = idx & 255;
    wt[idx] = f2bf(W[(size_t)k * HC + n]);
}

// ---------------------------------------------------------------------------
// K1 (MFMA): h = x @ W, bf16 in, fp32 accum; fused a_src/a_dst epilogue.
// ---------------------------------------------------------------------------
__global__ __launch_bounds__(256) void k1_mfma(const float* __restrict__ x,
                                               const uint16_t* __restrict__ wt,
                                               const float* __restrict__ att_src,
                                               const float* __restrict__ att_dst,
                                               uint16_t* __restrict__ hb,
                                               float* __restrict__ a_src,
                                               float* __restrict__ a_dst) {
    __shared__ char smem[64 * 528];   // xs(bf16 64x264) == hs(f32 64x132)
    __shared__ float att_s[HC], att_d[HC];
    uint16_t* xs = (uint16_t*)smem;
    float*    hs = (float*)smem;

    const int tid  = threadIdx.x;
    const int wave = tid >> 6;
    const int lane = tid & 63;
    const int m    = lane & 15;
    const int q    = lane >> 4;
    const int row0 = blockIdx.x * 64;

    if (tid < HC) { att_s[tid] = att_src[tid]; att_d[tid] = att_dst[tid]; }

    for (int i = tid * 4; i < 64 * IN_DIM; i += 1024) {
        int r = i >> 8, c = i & 255;
        int gr = row0 + r;
        float4 v = make_float4(0.f, 0.f, 0.f, 0.f);
        if (gr < N_NODES) v = *(const float4*)(x + (size_t)gr * IN_DIM + c);
        uint32_t lo = (uint32_t)f2bf(v.x) | ((uint32_t)f2bf(v.y) << 16);
        uint32_t hi = (uint32_t)f2bf(v.z) | ((uint32_t)f2bf(v.w) << 16);
        *(uint2*)(xs + r * XPAD + c) = make_uint2(lo, hi);
    }
    __syncthreads();

    f32x4 acc[8];
    #pragma unroll
    for (int t = 0; t < 8; ++t) acc[t] = (f32x4){0.f, 0.f, 0.f, 0.f};

    const int arow = wave * 16 + m;
    #pragma unroll
    for (int ks = 0; ks < IN_DIM; ks += 32) {
        bf16x8 a = *(const bf16x8*)(xs + arow * XPAD + ks + q * 8);
        #pragma unroll
        for (int t = 0; t < 8; ++t) {
            bf16x8 b = *(const bf16x8*)(wt + (size_t)(t * 16 + m) * IN_DIM + ks + q * 8);
            acc[t] = __builtin_amdgcn_mfma_f32_16x16x32_bf16(a, b, acc[t], 0, 0, 0);
        }
    }
    __syncthreads();

    // C/D: col = lane&15, row = (lane>>4)*4 + reg
    #pragma unroll
    for (int t = 0; t < 8; ++t)
        #pragma unroll
        for (int r = 0; r < 4; ++r)
            hs[(wave * 16 + q * 4 + r) * HPAD + t * 16 + m] = acc[t][r];
    __syncthreads();

    for (int i = tid * 4; i < 64 * HC; i += 1024) {
        int r = i >> 7, c = i & 127;
        if (row0 + r < N_NODES) {
            float4 v = *(const float4*)(hs + r * HPAD + c);
            uint32_t lo = (uint32_t)f2bf(v.x) | ((uint32_t)f2bf(v.y) << 16);
            uint32_t hi = (uint32_t)f2bf(v.z) | ((uint32_t)f2bf(v.w) << 16);
            *(uint2*)(hb + (size_t)(row0 + r) * HC + c) = make_uint2(lo, hi);
        }
    }
    {
        int r = tid >> 2, hd = tid & 3;
        if (row0 + r < N_NODES) {
            float s = 0.f, d = 0.f;
            #pragma unroll
            for (int j = 0; j < 32; ++j) {
                float v = hs[r * HPAD + hd * 32 + j];
                s = fmaf(v, att_s[hd * 32 + j], s);
                d = fmaf(v, att_d[hd * 32 + j], d);
            }
            a_src[(row0 + r) * NHEAD + hd] = s;
            a_dst[(row0 + r) * NHEAD + hd] = d;
        }
    }
}

// ---------------------------------------------------------------------------
// P3: bin edges into FIXED-STRIDE bucket regions (binned[b*CAP + pos]).
// word = src(16) | dstlocal(7)<<16 | bucket(9)<<23. One global atomic per
// (block,bucket). CHUNK=2048 -> 806 blocks (~3/CU) for latency hiding.
// ---------------------------------------------------------------------------
__global__ __launch_bounds__(256) void p3_bin(const int* __restrict__ ei,
                                              int* __restrict__ gcur,
                                              uint32_t* __restrict__ binned) {
    __shared__ int hist[NBUK];
    __shared__ int lcur[NBUK];
    const int tid = threadIdx.x;
    for (int i = tid; i < NBUK; i += 256) hist[i] = 0;
    __syncthreads();

    uint32_t wreg[EPT];
    const int base = blockIdx.x * CHUNK;
    #pragma unroll
    for (int k = 0; k < EPT; ++k) {
        int e = base + k * 256 + tid;
        uint32_t word = 0xFFFFFFFFu;
        if (e < TOT_E) {
            int src, dst;
            if (e < N_EDGES) { src = ei[e]; dst = ei[N_EDGES + e]; }
            else             { src = e - N_EDGES; dst = src; }
            int b = dst >> SHIFT;
            word = (uint32_t)src | ((uint32_t)(dst & (BSZ - 1)) << 16)
                 | ((uint32_t)b << 23);
            atomicAdd(&hist[b], 1);
        }
        wreg[k] = word;
    }
    __syncthreads();
    for (int i = tid; i < NBUK; i += 256) {
        int c = hist[i];
        lcur[i] = c ? atomicAdd(&gcur[i], c) : 0;   // within-bucket base
    }
    __syncthreads();
    #pragma unroll
    for (int k = 0; k < EPT; ++k) {
        uint32_t word = wreg[k];
        if (word != 0xFFFFFFFFu) {
            int b = (int)(word >> 23);
            int pos = atomicAdd(&lcur[b], 1);
            if (pos < CAP) binned[(size_t)b * CAP + pos] = word;
        }
    }
}

// ---------------------------------------------------------------------------
// P4: per-bucket (512 thr): LDS stage + 128-node count/scan -> rbeg/rend +
// per-node-grouped csr in the bucket's fixed-stride region.
// ---------------------------------------------------------------------------
__global__ __launch_bounds__(512) void p4_csr(const uint32_t* __restrict__ binned,
                                              const int* __restrict__ gcur,
                                              int* __restrict__ rbeg,
                                              int* __restrict__ rend,
                                              int* __restrict__ csr_src) {
    __shared__ uint32_t ew[CAP];   // 24 KB
    __shared__ int ncnt[BSZ];
    __shared__ int ncur[BSZ];
    __shared__ int wtot;
    const int b    = blockIdx.x;
    const int base = b * CAP;
    int cnt = gcur[b];
    if (cnt > CAP) cnt = CAP;
    const int tid  = threadIdx.x;

    if (tid < BSZ) ncnt[tid] = 0;
    __syncthreads();

    for (int i = tid; i < cnt; i += 512) {
        uint32_t word = binned[base + i];
        ew[i] = word;
        atomicAdd(&ncnt[(word >> 16) & (BSZ - 1)], 1);
    }
    __syncthreads();

    int v = 0, inc = 0;
    if (tid < BSZ) {
        v = ncnt[tid];
        inc = v;
        int lane = tid & 63;
        #pragma unroll
        for (int d = 1; d < 64; d <<= 1) {
            int t = __shfl_up(inc, d, 64);
            if (lane >= d) inc += t;
        }
        if (tid == 63) wtot = inc;
    }
    __syncthreads();
    if (tid < BSZ) {
        int ex = inc - v + ((tid >= 64) ? wtot : 0);
        int node = b * BSZ + tid;
        if (node < N_NODES) {
            rbeg[node] = base + ex;
            rend[node] = base + ex + v;
        }
        ncur[tid] = ex;
    }
    __syncthreads();

    for (int i = tid; i < cnt; i += 512) {
        uint32_t word = ew[i];
        int local = (word >> 16) & (BSZ - 1);
        int r = atomicAdd(&ncur[local], 1);
        csr_src[base + r] = (int)(word & 0xFFFFu);
    }
}

// ---------------------------------------------------------------------------
// K6: per-node softmax aggregation + bias + ELU. R4-winning config: 1 wave
// per node, unroll-4 (redundant per-lane exp buys memory-level parallelism),
// bf16 act output, hoisted base pointers.
// ---------------------------------------------------------------------------
__global__ __launch_bounds__(64) void k6_agg(const uint32_t* __restrict__ hb32,
                                             const float* __restrict__ a_src,
                                             const float* __restrict__ a_dst,
                                             const int* __restrict__ rbeg,
                                             const int* __restrict__ rend,
                                             const int* __restrict__ csr_src,
                                             const float* __restrict__ bias,
                                             uint32_t* __restrict__ actb) {
    const int node = blockIdx.x;
    const int lane = threadIdx.x;
    const int head = lane >> 4;

    const float ad  = a_dst[node * NHEAD + head];
    const uint32_t* hbl = hb32 + lane;
    const float*    ash = a_src + head;

    int p   = rbeg[node];
    const int end = rend[node];

    float l = 0.f, acc0 = 0.f, acc1 = 0.f;

    for (; p + 4 <= end; p += 4) {
        int s0 = csr_src[p + 0];
        int s1 = csr_src[p + 1];
        int s2 = csr_src[p + 2];
        int s3 = csr_src[p + 3];
        float e0 = ash[s0 * NHEAD] + ad;
        float e1 = ash[s1 * NHEAD] + ad;
        float e2 = ash[s2 * NHEAD] + ad;
        float e3 = ash[s3 * NHEAD] + ad;
        uint32_t u0 = hbl[(size_t)s0 * 64];
        uint32_t u1 = hbl[(size_t)s1 * 64];
        uint32_t u2 = hbl[(size_t)s2 * 64];
        uint32_t u3 = hbl[(size_t)s3 * 64];
        e0 = fmaxf(e0, 0.2f * e0);
        e1 = fmaxf(e1, 0.2f * e1);
        e2 = fmaxf(e2, 0.2f * e2);
        e3 = fmaxf(e3, 0.2f * e3);
        float w0 = __expf(e0), w1 = __expf(e1);
        float w2 = __expf(e2), w3 = __expf(e3);
        l += (w0 + w1) + (w2 + w3);
        acc0 = fmaf(w0, bf_lo(u0), acc0);
        acc1 = fmaf(w0, bf_hi(u0), acc1);
        acc0 = fmaf(w1, bf_lo(u1), acc0);
        acc1 = fmaf(w1, bf_hi(u1), acc1);
        acc0 = fmaf(w2, bf_lo(u2), acc0);
        acc1 = fmaf(w2, bf_hi(u2), acc1);
        acc0 = fmaf(w3, bf_lo(u3), acc0);
        acc1 = fmaf(w3, bf_hi(u3), acc1);
    }
    for (; p < end; ++p) {
        int s = csr_src[p];
        float e = ash[s * NHEAD] + ad;
        e = fmaxf(e, 0.2f * e);
        float w = __expf(e);
        uint32_t u = hbl[(size_t)s * 64];
        l += w;
        acc0 = fmaf(w, bf_lo(u), acc0);
        acc1 = fmaf(w, bf_hi(u), acc1);
    }

    const int c0 = lane << 1;
    float inv = 1.f / l;                    // self loop => l > 0
    float o0 = acc0 * inv + bias[c0];
    float o1 = acc1 * inv + bias[c0 + 1];
    o0 = (o0 > 0.f) ? o0 : (__expf(o0) - 1.f);
    o1 = (o1 > 0.f) ? o1 : (__expf(o1) - 1.f);
    actb[(size_t)node * 64 + lane] = (uint32_t)f2bf(o0) | ((uint32_t)f2bf(o1) << 16);
}

// ---------------------------------------------------------------------------
// K7: out = act @ lin_W + lin_b   [N,128] @ [128,64]; act read as bf16
// ---------------------------------------------------------------------------
__global__ __launch_bounds__(512) void k7_out(const uint32_t* __restrict__ actb,
                                              const float* __restrict__ linW,
                                              const float* __restrict__ linb,
                                              float* __restrict__ out) {
    __shared__ float sW[HC * OUT_DIM];   // 32 KB
    __shared__ float srow[32 * HC];      // 16 KB
    const int tid   = threadIdx.x;
    const int node0 = blockIdx.x * 32;

    for (int i = tid * 4; i < HC * OUT_DIM; i += 512 * 4)
        *(float4*)(sW + i) = *(const float4*)(linW + i);
    {
        int i = tid * 4;                 // word index: 32 rows x 64 words
        int r = i >> 6, cw = i & 63;
        int node = node0 + r;
        uint4 v = make_uint4(0, 0, 0, 0);
        if (node < N_NODES) v = *(const uint4*)(actb + (size_t)node * 64 + cw);
        float* d = srow + r * HC + cw * 2;
        d[0] = bf_lo(v.x); d[1] = bf_hi(v.x);
        d[2] = bf_lo(v.y); d[3] = bf_hi(v.y);
        d[4] = bf_lo(v.z); d[5] = bf_hi(v.z);
        d[6] = bf_lo(v.w); d[7] = bf_hi(v.w);
    }
    __syncthreads();

    const int r    = tid >> 4;
    const int colb = (tid & 15) << 2;
    float4 acc = *(const float4*)(linb + colb);
    const float* rp = srow + r * HC;

    #pragma unroll
    for (int k = 0; k < HC; k += 4) {
        float4 xv = *(const float4*)(rp + k);
        float4 w0 = *(const float4*)(sW + (k + 0) * OUT_DIM + colb);
        float4 w1 = *(const float4*)(sW + (k + 1) * OUT_DIM + colb);
        float4 w2 = *(const float4*)(sW + (k + 2) * OUT_DIM + colb);
        float4 w3 = *(const float4*)(sW + (k + 3) * OUT_DIM + colb);
        acc.x += xv.x * w0.x; acc.x += xv.y * w1.x; acc.x += xv.z * w2.x; acc.x += xv.w * w3.x;
        acc.y += xv.x * w0.y; acc.y += xv.y * w1.y; acc.y += xv.z * w2.y; acc.y += xv.w * w3.y;
        acc.z += xv.x * w0.z; acc.z += xv.y * w1.z; acc.z += xv.z * w2.z; acc.z += xv.w * w3.z;
        acc.w += xv.x * w0.w; acc.w += xv.y * w1.w; acc.w += xv.z * w2.w; acc.w += xv.w * w3.w;
    }

    int node = node0 + r;
    if (node < N_NODES)
        *(float4*)(out + (size_t)node * OUT_DIM + colb) = acc;
}

// ---------------------------------------------------------------------------
extern "C" void kernel_launch(void* const* d_in, const int* in_sizes, int n_in,
                              void* d_out, int out_size, void* d_ws, size_t ws_size,
                              hipStream_t stream) {
    (void)in_sizes; (void)n_in; (void)out_size; (void)ws_size;
    const float* x       = (const float*)d_in[0];
    const int*   ei      = (const int*)d_in[1];
    const float* W       = (const float*)d_in[2];
    const float* att_src = (const float*)d_in[3];
    const float* att_dst = (const float*)d_in[4];
    const float* bias    = (const float*)d_in[5];
    const float* linW    = (const float*)d_in[6];
    const float* linb    = (const float*)d_in[7];
    float*       out     = (float*)d_out;

    char*  ws  = (char*)d_ws;
    size_t off = 0;
    auto alloc = [&](size_t bytes) -> void* {
        void* p = ws + off;
        off += (bytes + 255) & ~(size_t)255;
        return p;
    };
    uint16_t* hb     = (uint16_t*)alloc((size_t)N_NODES * HC * 2);
    uint16_t* wt     = (uint16_t*)alloc((size_t)HC * IN_DIM * 2);
    uint32_t* actb   = (uint32_t*)alloc((size_t)N_NODES * 64 * 4);
    float*    a_src  = (float*)alloc((size_t)N_NODES * NHEAD * 4);
    float*    a_dst  = (float*)alloc((size_t)N_NODES * NHEAD * 4);
    int*      gcur   = (int*)alloc((size_t)NBUK * 4);
    int*      rbeg   = (int*)alloc((size_t)N_NODES * 4);
    int*      rend   = (int*)alloc((size_t)N_NODES * 4);
    uint32_t* binned = (uint32_t*)alloc((size_t)NBUK * CAP * 4);
    int*      csr    = (int*)alloc((size_t)NBUK * CAP * 4);

    hipMemsetAsync(gcur, 0, (size_t)NBUK * 4, stream);

    w2bf<<<(HC * IN_DIM) / 256, 256, 0, stream>>>(W, wt);
    k1_mfma<<<(N_NODES + 63) / 64, 256, 0, stream>>>(x, wt, att_src, att_dst,
                                                     hb, a_src, a_dst);
    p3_bin<<<NCHUNK, 256, 0, stream>>>(ei, gcur, binned);
    p4_csr<<<NBUK, 512, 0, stream>>>(binned, gcur, rbeg, rend, csr);
    k6_agg<<<N_NODES, 64, 0, stream>>>((const uint32_t*)hb, a_src, a_dst,
                                       rbeg, rend, csr, bias, actb);
    k7_out<<<(N_NODES + 31) / 32, 512, 0, stream>>>(actb, linW, linb, out);
}

// Round 8
// 244.519 us; speedup vs baseline: 1.1890x; 1.0842x over previous
//
#include <hip/hip_runtime.h>
#include <cstdint>
#include <cstddef>

#define N_NODES 50000
#define N_EDGES 1600000
#define TOT_E   (N_EDGES + N_NODES)
#define IN_DIM  256
#define HC      128
#define NHEAD   4
#define OUT_DIM 64

// bucket-radix CSR build (fixed-stride buckets)
#define SHIFT   7
#define BSZ     128
#define NBUK    ((N_NODES + BSZ - 1) / BSZ)      // 391
#define CHUNK   2048
#define EPT     8                                // CHUNK / 256
#define NCHUNK  ((TOT_E + CHUNK - 1) / CHUNK)    // 806
#define CAP     6144                             // bucket cap (mean 4220, +29 sd)
#define QCAP    1792                             // quarter-bucket cap (mean 1088, +21 sd)

// k1 MFMA tiling
#define XPAD 264   // bf16 elems per LDS row (256 + 8)
#define HPAD 132   // fp32 elems per LDS row in epilogue (128 + 4)
#define K1_NB ((N_NODES + 63) / 64)              // 782

typedef __attribute__((ext_vector_type(8))) short bf16x8;
typedef __attribute__((ext_vector_type(4))) float f32x4;

static __device__ __forceinline__ uint16_t f2bf(float f) {
    uint32_t u = __float_as_uint(f);
    uint32_t r = (u + 0x7fffu + ((u >> 16) & 1u)) >> 16;   // RNE
    return (uint16_t)r;
}
static __device__ __forceinline__ float bf_lo(uint32_t u) {
    return __uint_as_float(u << 16);
}
static __device__ __forceinline__ float bf_hi(uint32_t u) {
    return __uint_as_float(u & 0xffff0000u);
}

// ---------------------------------------------------------------------------
// W prep: W fp32 [256][128] -> W^T bf16 [128][256]; also zeroes gcur
// (folds the memset dispatch).
// ---------------------------------------------------------------------------
__global__ __launch_bounds__(256) void w2bf(const float* __restrict__ W,
                                            uint16_t* __restrict__ wt,
                                            int* __restrict__ gcur) {
    int idx = blockIdx.x * 256 + threadIdx.x;   // n*256 + k
    int n = idx >> 8, k = idx & 255;
    wt[idx] = f2bf(W[(size_t)k * HC + n]);
    if (idx < NBUK) gcur[idx] = 0;
}

// ---------------------------------------------------------------------------
// K1P3 (grid-fused): blocks [0, K1_NB) run the MFMA GEMM (h=x@W bf16 +
// fused a_src/a_dst); blocks [K1_NB, K1_NB+NCHUNK) run the edge binning.
// Independent work on different pipes -> p3 blocks backfill as k1 retires.
// ---------------------------------------------------------------------------
__global__ __launch_bounds__(256) void k1p3(const float* __restrict__ x,
                                            const uint16_t* __restrict__ wt,
                                            const float* __restrict__ att_src,
                                            const float* __restrict__ att_dst,
                                            uint16_t* __restrict__ hb,
                                            float* __restrict__ a_src,
                                            float* __restrict__ a_dst,
                                            const int* __restrict__ ei,
                                            int* __restrict__ gcur,
                                            uint32_t* __restrict__ binned) {
    __shared__ char smem[64 * 528];   // k1: xs(bf16 64x264)==hs(f32 64x132); p3: hist+lcur
    __shared__ float att_s[HC], att_d[HC];
    const int tid = threadIdx.x;

    if (blockIdx.x < K1_NB) {
        // ---------------- k1: MFMA GEMM ----------------
        uint16_t* xs = (uint16_t*)smem;
        float*    hs = (float*)smem;
        const int wave = tid >> 6;
        const int lane = tid & 63;
        const int m    = lane & 15;
        const int q    = lane >> 4;
        const int row0 = blockIdx.x * 64;

        if (tid < HC) { att_s[tid] = att_src[tid]; att_d[tid] = att_dst[tid]; }

        for (int i = tid * 4; i < 64 * IN_DIM; i += 1024) {
            int r = i >> 8, c = i & 255;
            int gr = row0 + r;
            float4 v = make_float4(0.f, 0.f, 0.f, 0.f);
            if (gr < N_NODES) v = *(const float4*)(x + (size_t)gr * IN_DIM + c);
            uint32_t lo = (uint32_t)f2bf(v.x) | ((uint32_t)f2bf(v.y) << 16);
            uint32_t hi = (uint32_t)f2bf(v.z) | ((uint32_t)f2bf(v.w) << 16);
            *(uint2*)(xs + r * XPAD + c) = make_uint2(lo, hi);
        }
        __syncthreads();

        f32x4 acc[8];
        #pragma unroll
        for (int t = 0; t < 8; ++t) acc[t] = (f32x4){0.f, 0.f, 0.f, 0.f};

        const int arow = wave * 16 + m;
        #pragma unroll
        for (int ks = 0; ks < IN_DIM; ks += 32) {
            bf16x8 a = *(const bf16x8*)(xs + arow * XPAD + ks + q * 8);
            #pragma unroll
            for (int t = 0; t < 8; ++t) {
                bf16x8 b = *(const bf16x8*)(wt + (size_t)(t * 16 + m) * IN_DIM + ks + q * 8);
                acc[t] = __builtin_amdgcn_mfma_f32_16x16x32_bf16(a, b, acc[t], 0, 0, 0);
            }
        }
        __syncthreads();

        // C/D: col = lane&15, row = (lane>>4)*4 + reg
        #pragma unroll
        for (int t = 0; t < 8; ++t)
            #pragma unroll
            for (int r = 0; r < 4; ++r)
                hs[(wave * 16 + q * 4 + r) * HPAD + t * 16 + m] = acc[t][r];
        __syncthreads();

        for (int i = tid * 4; i < 64 * HC; i += 1024) {
            int r = i >> 7, c = i & 127;
            if (row0 + r < N_NODES) {
                float4 v = *(const float4*)(hs + r * HPAD + c);
                uint32_t lo = (uint32_t)f2bf(v.x) | ((uint32_t)f2bf(v.y) << 16);
                uint32_t hi = (uint32_t)f2bf(v.z) | ((uint32_t)f2bf(v.w) << 16);
                *(uint2*)(hb + (size_t)(row0 + r) * HC + c) = make_uint2(lo, hi);
            }
        }
        {
            int r = tid >> 2, hd = tid & 3;
            if (row0 + r < N_NODES) {
                float s = 0.f, d = 0.f;
                #pragma unroll
                for (int j = 0; j < 32; ++j) {
                    float v = hs[r * HPAD + hd * 32 + j];
                    s = fmaf(v, att_s[hd * 32 + j], s);
                    d = fmaf(v, att_d[hd * 32 + j], d);
                }
                a_src[(row0 + r) * NHEAD + hd] = s;
                a_dst[(row0 + r) * NHEAD + hd] = d;
            }
        }
    } else {
        // ---------------- p3: bin edges into fixed-stride bucket regions ----
        int* hist = (int*)smem;
        int* lcur = hist + NBUK;
        for (int i = tid; i < NBUK; i += 256) hist[i] = 0;
        __syncthreads();

        uint32_t wreg[EPT];
        const int base = (blockIdx.x - K1_NB) * CHUNK;
        #pragma unroll
        for (int k = 0; k < EPT; ++k) {
            int e = base + k * 256 + tid;
            uint32_t word = 0xFFFFFFFFu;
            if (e < TOT_E) {
                int src, dst;
                if (e < N_EDGES) { src = ei[e]; dst = ei[N_EDGES + e]; }
                else             { src = e - N_EDGES; dst = src; }
                int b = dst >> SHIFT;
                word = (uint32_t)src | ((uint32_t)(dst & (BSZ - 1)) << 16)
                     | ((uint32_t)b << 23);
                atomicAdd(&hist[b], 1);
            }
            wreg[k] = word;
        }
        __syncthreads();
        for (int i = tid; i < NBUK; i += 256) {
            int c = hist[i];
            lcur[i] = c ? atomicAdd(&gcur[i], c) : 0;   // within-bucket base
        }
        __syncthreads();
        #pragma unroll
        for (int k = 0; k < EPT; ++k) {
            uint32_t word = wreg[k];
            if (word != 0xFFFFFFFFu) {
                int b = (int)(word >> 23);
                int pos = atomicAdd(&lcur[b], 1);
                if (pos < CAP) binned[(size_t)b * CAP + pos] = word;
            }
        }
    }
}

// ---------------------------------------------------------------------------
// Q4 (fused p4+k6): 4 quarter-blocks per bucket. Each streams the bucket's
// binned region, keeps its 32 nodes' edges in LDS (append -> count -> scan
// -> regroup), then runs the R7 gather loop with edge srcs from LDS.
// No global csr array at all. Block = 256 thr = 4 waves x 8 nodes.
// ---------------------------------------------------------------------------
__global__ __launch_bounds__(256) void q4_agg(const uint32_t* __restrict__ binned,
                                              const int* __restrict__ gcur,
                                              const uint32_t* __restrict__ hb32,
                                              const float* __restrict__ a_src,
                                              const float* __restrict__ a_dst,
                                              const float* __restrict__ bias,
                                              uint32_t* __restrict__ actb) {
    __shared__ uint32_t ewb[QCAP];   // 7 KB: unordered append of this quarter's edges
    __shared__ uint32_t ew2[QCAP];   // 7 KB: grouped by local node (src only)
    __shared__ int ncnt[32], nbeg[32], ncur[32];
    __shared__ int tot;
    const int b   = blockIdx.x >> 2;
    const int sub = blockIdx.x & 3;
    const int tid = threadIdx.x;

    int cnt = gcur[b];
    if (cnt > CAP) cnt = CAP;
    if (tid == 0) tot = 0;
    if (tid < 32) ncnt[tid] = 0;
    __syncthreads();

    const uint32_t* bb = binned + (size_t)b * CAP;
    for (int i = tid; i < cnt; i += 256) {
        uint32_t word = bb[i];
        int dl = (word >> 16) & 127;
        if ((dl >> 5) == sub) {
            int pos = atomicAdd(&tot, 1);
            if (pos < QCAP) ewb[pos] = word;
            atomicAdd(&ncnt[dl & 31], 1);
        }
    }
    __syncthreads();
    int T = tot;
    if (T > QCAP) T = QCAP;

    if (tid < 32) {                       // inclusive scan of 32 counts
        int v = ncnt[tid];
        int inc = v;
        #pragma unroll
        for (int d = 1; d < 32; d <<= 1) {
            int t = __shfl_up(inc, d, 64);
            if (tid >= d) inc += t;
        }
        nbeg[tid] = inc - v;
        ncur[tid] = inc - v;
    }
    __syncthreads();
    for (int i = tid; i < T; i += 256) {
        uint32_t word = ewb[i];
        int ln  = (word >> 16) & 31;
        int pos = atomicAdd(&ncur[ln], 1);
        ew2[pos] = word & 0xFFFFu;        // src only
    }
    __syncthreads();

    // gather: wave w handles local nodes w*8 .. w*8+7
    const int wave = tid >> 6;
    const int lane = tid & 63;
    const int head = lane >> 4;
    const uint32_t* hbl = hb32 + lane;
    const float*    ash = a_src + head;

    for (int k = 0; k < 8; ++k) {
        const int ln   = wave * 8 + k;
        const int node = b * BSZ + sub * 32 + ln;
        if (node >= N_NODES) continue;

        const float ad = a_dst[node * NHEAD + head];
        int p = nbeg[ln];
        const int end = p + ncnt[ln];

        float l = 0.f, acc0 = 0.f, acc1 = 0.f;

        for (; p + 4 <= end; p += 4) {
            int s0 = (int)ew2[p + 0];
            int s1 = (int)ew2[p + 1];
            int s2 = (int)ew2[p + 2];
            int s3 = (int)ew2[p + 3];
            float e0 = ash[s0 * NHEAD] + ad;
            float e1 = ash[s1 * NHEAD] + ad;
            float e2 = ash[s2 * NHEAD] + ad;
            float e3 = ash[s3 * NHEAD] + ad;
            uint32_t u0 = hbl[(size_t)s0 * 64];
            uint32_t u1 = hbl[(size_t)s1 * 64];
            uint32_t u2 = hbl[(size_t)s2 * 64];
            uint32_t u3 = hbl[(size_t)s3 * 64];
            e0 = fmaxf(e0, 0.2f * e0);
            e1 = fmaxf(e1, 0.2f * e1);
            e2 = fmaxf(e2, 0.2f * e2);
            e3 = fmaxf(e3, 0.2f * e3);
            float w0 = __expf(e0), w1 = __expf(e1);
            float w2 = __expf(e2), w3 = __expf(e3);
            l += (w0 + w1) + (w2 + w3);
            acc0 = fmaf(w0, bf_lo(u0), acc0);
            acc1 = fmaf(w0, bf_hi(u0), acc1);
            acc0 = fmaf(w1, bf_lo(u1), acc0);
            acc1 = fmaf(w1, bf_hi(u1), acc1);
            acc0 = fmaf(w2, bf_lo(u2), acc0);
            acc1 = fmaf(w2, bf_hi(u2), acc1);
            acc0 = fmaf(w3, bf_lo(u3), acc0);
            acc1 = fmaf(w3, bf_hi(u3), acc1);
        }
        for (; p < end; ++p) {
            int s = (int)ew2[p];
            float e = ash[s * NHEAD] + ad;
            e = fmaxf(e, 0.2f * e);
            float w = __expf(e);
            uint32_t u = hbl[(size_t)s * 64];
            l += w;
            acc0 = fmaf(w, bf_lo(u), acc0);
            acc1 = fmaf(w, bf_hi(u), acc1);
        }

        const int c0 = lane << 1;
        float inv = 1.f / l;              // self loop => l > 0
        float o0 = acc0 * inv + bias[c0];
        float o1 = acc1 * inv + bias[c0 + 1];
        o0 = (o0 > 0.f) ? o0 : (__expf(o0) - 1.f);
        o1 = (o1 > 0.f) ? o1 : (__expf(o1) - 1.f);
        actb[(size_t)node * 64 + lane] = (uint32_t)f2bf(o0) | ((uint32_t)f2bf(o1) << 16);
    }
}

// ---------------------------------------------------------------------------
// K7: out = act @ lin_W + lin_b   [N,128] @ [128,64]; act read as bf16
// ---------------------------------------------------------------------------
__global__ __launch_bounds__(512) void k7_out(const uint32_t* __restrict__ actb,
                                              const float* __restrict__ linW,
                                              const float* __restrict__ linb,
                                              float* __restrict__ out) {
    __shared__ float sW[HC * OUT_DIM];   // 32 KB
    __shared__ float srow[32 * HC];      // 16 KB
    const int tid   = threadIdx.x;
    const int node0 = blockIdx.x * 32;

    for (int i = tid * 4; i < HC * OUT_DIM; i += 512 * 4)
        *(float4*)(sW + i) = *(const float4*)(linW + i);
    {
        int i = tid * 4;                 // word index: 32 rows x 64 words
        int r = i >> 6, cw = i & 63;
        int node = node0 + r;
        uint4 v = make_uint4(0, 0, 0, 0);
        if (node < N_NODES) v = *(const uint4*)(actb + (size_t)node * 64 + cw);
        float* d = srow + r * HC + cw * 2;
        d[0] = bf_lo(v.x); d[1] = bf_hi(v.x);
        d[2] = bf_lo(v.y); d[3] = bf_hi(v.y);
        d[4] = bf_lo(v.z); d[5] = bf_hi(v.z);
        d[6] = bf_lo(v.w); d[7] = bf_hi(v.w);
    }
    __syncthreads();

    const int r    = tid >> 4;
    const int colb = (tid & 15) << 2;
    float4 acc = *(const float4*)(linb + colb);
    const float* rp = srow + r * HC;

    #pragma unroll
    for (int k = 0; k < HC; k += 4) {
        float4 xv = *(const float4*)(rp + k);
        float4 w0 = *(const float4*)(sW + (k + 0) * OUT_DIM + colb);
        float4 w1 = *(const float4*)(sW + (k + 1) * OUT_DIM + colb);
        float4 w2 = *(const float4*)(sW + (k + 2) * OUT_DIM + colb);
        float4 w3 = *(const float4*)(sW + (k + 3) * OUT_DIM + colb);
        acc.x += xv.x * w0.x; acc.x += xv.y * w1.x; acc.x += xv.z * w2.x; acc.x += xv.w * w3.x;
        acc.y += xv.x * w0.y; acc.y += xv.y * w1.y; acc.y += xv.z * w2.y; acc.y += xv.w * w3.y;
        acc.z += xv.x * w0.z; acc.z += xv.y * w1.z; acc.z += xv.z * w2.z; acc.z += xv.w * w3.z;
        acc.w += xv.x * w0.w; acc.w += xv.y * w1.w; acc.w += xv.z * w2.w; acc.w += xv.w * w3.w;
    }

    int node = node0 + r;
    if (node < N_NODES)
        *(float4*)(out + (size_t)node * OUT_DIM + colb) = acc;
}

// ---------------------------------------------------------------------------
extern "C" void kernel_launch(void* const* d_in, const int* in_sizes, int n_in,
                              void* d_out, int out_size, void* d_ws, size_t ws_size,
                              hipStream_t stream) {
    (void)in_sizes; (void)n_in; (void)out_size; (void)ws_size;
    const float* x       = (const float*)d_in[0];
    const int*   ei      = (const int*)d_in[1];
    const float* W       = (const float*)d_in[2];
    const float* att_src = (const float*)d_in[3];
    const float* att_dst = (const float*)d_in[4];
    const float* bias    = (const float*)d_in[5];
    const float* linW    = (const float*)d_in[6];
    const float* linb    = (const float*)d_in[7];
    float*       out     = (float*)d_out;

    char*  ws  = (char*)d_ws;
    size_t off = 0;
    auto alloc = [&](size_t bytes) -> void* {
        void* p = ws + off;
        off += (bytes + 255) & ~(size_t)255;
        return p;
    };
    uint16_t* hb     = (uint16_t*)alloc((size_t)N_NODES * HC * 2);
    uint16_t* wt     = (uint16_t*)alloc((size_t)HC * IN_DIM * 2);
    uint32_t* actb   = (uint32_t*)alloc((size_t)N_NODES * 64 * 4);
    float*    a_src  = (float*)alloc((size_t)N_NODES * NHEAD * 4);
    float*    a_dst  = (float*)alloc((size_t)N_NODES * NHEAD * 4);
    int*      gcur   = (int*)alloc((size_t)NBUK * 4);
    uint32_t* binned = (uint32_t*)alloc((size_t)NBUK * CAP * 4);

    w2bf<<<(HC * IN_DIM) / 256, 256, 0, stream>>>(W, wt, gcur);
    k1p3<<<K1_NB + NCHUNK, 256, 0, stream>>>(x, wt, att_src, att_dst,
                                             hb, a_src, a_dst,
                                             ei, gcur, binned);
    q4_agg<<<NBUK * 4, 256, 0, stream>>>(binned, gcur, (const uint32_t*)hb,
                                         a_src, a_dst, bias, actb);
    k7_out<<<(N_NODES + 31) / 32, 512, 0, stream>>>(actb, linW, linb, out);
}